// Round 12
// baseline (181.022 us; speedup 1.0000x reference)
//
#include <hip/hip_runtime.h>

#define N_NODES 50000
#define N_EDGES 800000
#define IN_DIM 128
#define HID 64
#define NT 32        // nodes per block in gin layer
#define RST_PITCH 68 // 272B rows: 16B-aligned, conflict-free broadcasts
#define NXCD 8
#define RANGE (N_NODES / NXCD)             // 6250 nodes per range (25KB LDS)
#define NCHUNK 32
#define EDGES_PER_CHUNK (N_EDGES / NCHUNK) // 25000
#define I4_PER_CHUNK (EDGES_PER_CHUNK / 4) // 6250
#define NBLK_N 196                         // ceil(N_NODES/256)
#define FC_BLOCKS 782                      // ceil(N_NODES/64)

using v4f = __attribute__((ext_vector_type(4))) float;
using v4i = __attribute__((ext_vector_type(4))) int;
using v4u = __attribute__((ext_vector_type(4))) unsigned;

// bf16x4 -> uint2 (RNE pack)
static __device__ inline uint2 pack4(v4f v) {
    unsigned u0 = __float_as_uint(v[0]);
    unsigned u1 = __float_as_uint(v[1]);
    unsigned u2 = __float_as_uint(v[2]);
    unsigned u3 = __float_as_uint(v[3]);
    uint2 r;
    r.x = ((u0 + 0x7FFFu + ((u0 >> 16) & 1)) >> 16) |
          ((u1 + 0x7FFFu + ((u1 >> 16) & 1)) & 0xFFFF0000u);
    r.y = ((u2 + 0x7FFFu + ((u2 >> 16) & 1)) >> 16) |
          ((u3 + 0x7FFFu + ((u3 >> 16) & 1)) & 0xFFFF0000u);
    return r;
}
// uint4 (8 bf16) -> 2x v4f
static __device__ inline void unpack8(v4u p, v4f& lo, v4f& hi) {
    lo[0] = __uint_as_float(p[0] << 16);
    lo[1] = __uint_as_float(p[0] & 0xFFFF0000u);
    lo[2] = __uint_as_float(p[1] << 16);
    lo[3] = __uint_as_float(p[1] & 0xFFFF0000u);
    hi[0] = __uint_as_float(p[2] << 16);
    hi[1] = __uint_as_float(p[2] & 0xFFFF0000u);
    hi[2] = __uint_as_float(p[3] << 16);
    hi[3] = __uint_as_float(p[3] & 0xFFFF0000u);
}

// ---------------- fused fc_init + hist ----------------
// blocks [0,782): h0 = relu(feat @ fc_w + fc_b), fp32 + bf16 mirror.
// blocks [782,1038): dst histogram chunk into LDS, dump to H.
// Independent subsystems co-resident -> hist hides under the fc GEMM.

#define FT_PITCH 132

__global__ __launch_bounds__(256) void fc_hist_kernel(
        const float* __restrict__ feat, const float* __restrict__ W,
        const float* __restrict__ bias, float* __restrict__ hf,
        unsigned* __restrict__ hb,
        const int* __restrict__ dst, int* __restrict__ H, int n) {
    __shared__ char smem[66560];   // fc: 32KB Wl + 33KB ft ; hist: 25KB cnt

    if (blockIdx.x >= FC_BLOCKS) {
        // ---- hist path ----
        int* cnt = (int*)smem;
        int hb_id = blockIdx.x - FC_BLOCKS;
        int r = hb_id & (NXCD - 1), c = hb_id >> 3;
        int lo = r * RANGE;
        for (int i = threadIdx.x; i < RANGE; i += 256) cnt[i] = 0;
        __syncthreads();
        const v4i* d4p = reinterpret_cast<const v4i*>(dst) + c * I4_PER_CHUNK;
#pragma unroll 2
        for (int i = threadIdx.x; i < I4_PER_CHUNK; i += 256) {
            v4i d4 = d4p[i];
            int a;
            a = d4.x - lo; if ((unsigned)a < RANGE) atomicAdd(&cnt[a], 1);
            a = d4.y - lo; if ((unsigned)a < RANGE) atomicAdd(&cnt[a], 1);
            a = d4.z - lo; if ((unsigned)a < RANGE) atomicAdd(&cnt[a], 1);
            a = d4.w - lo; if ((unsigned)a < RANGE) atomicAdd(&cnt[a], 1);
        }
        __syncthreads();
        int* Hrow = H + (size_t)c * N_NODES + lo;
        for (int i = threadIdx.x; i < RANGE; i += 256) Hrow[i] = cnt[i];
        return;
    }

    // ---- fc path ----
    float* Wl = (float*)smem;                 // 32 KB
    float* ft = (float*)(smem + 32768);       // 33 KB
    int base = blockIdx.x * 64;
    for (int i = threadIdx.x; i < IN_DIM * HID / 4; i += 256)
        *reinterpret_cast<v4f*>(&Wl[i * 4]) = *reinterpret_cast<const v4f*>(&W[i * 4]);
    {
        int f4 = threadIdx.x & 31;
        int r0 = threadIdx.x >> 5;
        for (int p = 0; p < 8; ++p) {
            int r = p * 8 + r0;
            int node = base + r;
            v4f v = {0.f, 0.f, 0.f, 0.f};
            if (node < n)
                v = *reinterpret_cast<const v4f*>(&feat[(size_t)node * IN_DIM + f4 * 4]);
            *reinterpret_cast<v4f*>(&ft[r * FT_PITCH + f4 * 4]) = v;
        }
    }
    __syncthreads();

    int tx = threadIdx.x & 15;
    int ty = threadIdx.x >> 4;
    v4f acc[4];
    v4f b4 = *reinterpret_cast<const v4f*>(&bias[tx * 4]);
    acc[0] = b4; acc[1] = b4; acc[2] = b4; acc[3] = b4;

#pragma unroll 16
    for (int k = 0; k < IN_DIM; ++k) {
        v4f w4 = *reinterpret_cast<const v4f*>(&Wl[k * HID + tx * 4]);
        float a0 = ft[(ty * 4 + 0) * FT_PITCH + k];
        float a1 = ft[(ty * 4 + 1) * FT_PITCH + k];
        float a2 = ft[(ty * 4 + 2) * FT_PITCH + k];
        float a3 = ft[(ty * 4 + 3) * FT_PITCH + k];
        acc[0] += a0 * w4;
        acc[1] += a1 * w4;
        acc[2] += a2 * w4;
        acc[3] += a3 * w4;
    }
#pragma unroll
    for (int i = 0; i < 4; ++i) {
        int node = base + ty * 4 + i;
        if (node < n) {
            v4f o;
            o[0] = fmaxf(acc[i][0], 0.f);
            o[1] = fmaxf(acc[i][1], 0.f);
            o[2] = fmaxf(acc[i][2], 0.f);
            o[3] = fmaxf(acc[i][3], 0.f);
            *reinterpret_cast<v4f*>(&hf[(size_t)node * HID + tx * 4]) = o;
            *reinterpret_cast<uint2*>(&hb[(size_t)node * 32 + tx * 2]) = pack4(o);
        }
    }
}

// ---------------- CSR scans ----------------

__global__ void scanA_kernel(const int* __restrict__ H, int* __restrict__ row_ptr,
                             int* __restrict__ blksum,
                             unsigned* __restrict__ hbA, unsigned* __restrict__ hbB) {
    __shared__ int sh[256];
    int t = threadIdx.x;
    int node = blockIdx.x * 256 + t;
    int d = 0;
    if (node < N_NODES)
#pragma unroll 8
        for (int c = 0; c < NCHUNK; ++c) d += H[(size_t)c * N_NODES + node];
    sh[t] = d;
    __syncthreads();
    for (int off = 1; off < 256; off <<= 1) {
        int add = (t >= off) ? sh[t - off] : 0;
        __syncthreads();
        sh[t] += add;
        __syncthreads();
    }
    int incl = sh[t];
    if (node < N_NODES) row_ptr[node] = incl - d;
    if (t == 255) blksum[blockIdx.x] = incl;
    if (blockIdx.x == 0 && t < 32) {
        hbA[(size_t)N_NODES * 32 + t] = 0u;
        hbB[(size_t)N_NODES * 32 + t] = 0u;
    }
}

__global__ void scanB_kernel(const int* __restrict__ H, int* __restrict__ row_ptr,
                             int* __restrict__ P, const int* __restrict__ blksum) {
    __shared__ int sh[256];
    int t = threadIdx.x;
    int v = (t < NBLK_N) ? blksum[t] : 0;
    sh[t] = v;
    __syncthreads();
    for (int off = 1; off < 256; off <<= 1) {
        int add = (t >= off) ? sh[t - off] : 0;
        __syncthreads();
        sh[t] += add;
        __syncthreads();
    }
    int excl = sh[t] - v;
    __syncthreads();
    sh[t] = excl;
    __syncthreads();
    int node = blockIdx.x * 256 + t;
    if (node < N_NODES) {
        int run = row_ptr[node] + sh[blockIdx.x];
        row_ptr[node] = run;
#pragma unroll 8
        for (int c = 0; c < NCHUNK; ++c) {
            P[(size_t)c * N_NODES + node] = run;
            run += H[(size_t)c * N_NODES + node];
        }
    }
    if (node == 0) row_ptr[N_NODES] = N_EDGES;
}

// place edges: LDS cursors (no global atomics); blockIdx%8 = range -> XCD
// affinity keeps each range's col segment in one L2.
__global__ __launch_bounds__(256) void place_kernel(
        const int* __restrict__ src, const int* __restrict__ dst,
        const int* __restrict__ P, int* __restrict__ col) {
    __shared__ int cur[RANGE];
    int r = blockIdx.x & (NXCD - 1), c = blockIdx.x >> 3;
    int lo = r * RANGE;
    const int* Pc = P + (size_t)c * N_NODES + lo;
    for (int i = threadIdx.x; i < RANGE; i += 256) cur[i] = Pc[i];
    __syncthreads();
    const v4i* d4p = reinterpret_cast<const v4i*>(dst) + c * I4_PER_CHUNK;
    const v4i* s4p = reinterpret_cast<const v4i*>(src) + c * I4_PER_CHUNK;
#pragma unroll 2
    for (int i = threadIdx.x; i < I4_PER_CHUNK; i += 256) {
        v4i d4 = d4p[i];
        v4i s4 = s4p[i];
        int a;
        a = d4.x - lo; if ((unsigned)a < RANGE) col[atomicAdd(&cur[a], 1)] = s4.x;
        a = d4.y - lo; if ((unsigned)a < RANGE) col[atomicAdd(&cur[a], 1)] = s4.y;
        a = d4.z - lo; if ((unsigned)a < RANGE) col[atomicAdd(&cur[a], 1)] = s4.z;
        a = d4.w - lo; if ((unsigned)a < RANGE) col[atomicAdd(&cur[a], 1)] = s4.w;
    }
}

// ---------------- fused GIN layer (512 threads, NT=32) ----------------
// Phase A: 8 waves x 4 nodes as 2 pairs. Gather reads the bf16 mirror with
// uint4 loads: 8 lanes cover a 128B row -> ONE load instruction fetches 8
// edges (lane: slot sl=lane&7, subgroup gx=lane>>3). j-loop unrolled x2 with
// split accumulators -> 4 independent 16B loads in flight. Reduce:
// shfl_xor 8/16/32. Tail/overshoot reads zero pad row n (convergent shfl).
// Phase B: 32x64x64 GEMM, 1 node x 4 outputs per thread, W in LDS.

template<bool FINAL>
__global__ __launch_bounds__(512) void gin_layer_kernel(
        const float* __restrict__ hf_in, const unsigned* __restrict__ hb_in,
        const int* __restrict__ row_ptr, const int* __restrict__ col,
        const float* __restrict__ W, const float* __restrict__ bias,
        const float* __restrict__ eps_arr, int layer,
        float* __restrict__ hf_out, unsigned* __restrict__ hb_out, int n) {
    __shared__ float Wl[HID * HID];         // 16 KB
    __shared__ float rst[NT * RST_PITCH];   // 8.7 KB

    for (int i = threadIdx.x; i < HID * HID / 4; i += 512)
        *reinterpret_cast<v4f*>(&Wl[i * 4]) = *reinterpret_cast<const v4f*>(&W[i * 4]);

    int wid = threadIdx.x >> 6, lane = threadIdx.x & 63;
    int gx = lane >> 3;         // edge subgroup 0..7
    int sl = lane & 7;          // uint4 slot in row
    int bo = sl * 4;            // uint offset in 32-uint bf16 row
    int base = blockIdx.x * NT;
    int n0 = base + wid * 4;    // this wave's 4 nodes
    float eps1 = 1.f + eps_arr[layer];

#pragma unroll
    for (int p = 0; p < 2; ++p) {
        int na = n0 + p * 2, nb = na + 1;
        bool va = na < n, vb = nb < n;
        int s0a = 0, s1a = 0, s0b = 0, s1b = 0;
        if (va) { s0a = row_ptr[na]; s1a = row_ptr[na + 1]; }
        if (vb) { s0b = row_ptr[nb]; s1b = row_ptr[nb + 1]; }
        int da = s1a - s0a, db = s1b - s0b;
        int ca = da > 64 ? 64 : da;
        int cb = db > 64 ? 64 : db;
        int myca = (va && lane < ca) ? col[s0a + lane] : n;   // pad -> zero row
        int mycb = (vb && lane < cb) ? col[s0b + lane] : n;
        v4f aL0 = {0.f,0.f,0.f,0.f}, aH0 = aL0, aL1 = aL0, aH1 = aL0;
        v4f bL0 = aL0, bH0 = aL0, bL1 = aL0, bH1 = aL0;
        int jma = (ca + 7) >> 3, jmb = (cb + 7) >> 3;
        int jm = jma > jmb ? jma : jmb;                       // <= 8
        int j = 0;
        for (; j + 2 <= jm; j += 2) {
            int i0 = j * 8 + gx, i1 = i0 + 8;                 // <= 63
            int sa0 = __shfl(myca, i0);                       // convergent
            int sb0 = __shfl(mycb, i0);
            int sa1 = __shfl(myca, i1);
            int sb1 = __shfl(mycb, i1);
            v4u pa0 = *reinterpret_cast<const v4u*>(&hb_in[(size_t)sa0 * 32 + bo]);
            v4u pb0 = *reinterpret_cast<const v4u*>(&hb_in[(size_t)sb0 * 32 + bo]);
            v4u pa1 = *reinterpret_cast<const v4u*>(&hb_in[(size_t)sa1 * 32 + bo]);
            v4u pb1 = *reinterpret_cast<const v4u*>(&hb_in[(size_t)sb1 * 32 + bo]);
            v4f lo, hi;
            unpack8(pa0, lo, hi); aL0 += lo; aH0 += hi;
            unpack8(pb0, lo, hi); bL0 += lo; bH0 += hi;
            unpack8(pa1, lo, hi); aL1 += lo; aH1 += hi;
            unpack8(pb1, lo, hi); bL1 += lo; bH1 += hi;
        }
        if (j < jm) {
            int i0 = j * 8 + gx;
            int sa0 = __shfl(myca, i0);
            int sb0 = __shfl(mycb, i0);
            v4u pa0 = *reinterpret_cast<const v4u*>(&hb_in[(size_t)sa0 * 32 + bo]);
            v4u pb0 = *reinterpret_cast<const v4u*>(&hb_in[(size_t)sb0 * 32 + bo]);
            v4f lo, hi;
            unpack8(pa0, lo, hi); aL0 += lo; aH0 += hi;
            unpack8(pb0, lo, hi); bL0 += lo; bH0 += hi;
        }
        // remainder chunks (degree > 64) — rare, per node
        for (int e0 = s0a + 64; e0 < s1a; e0 += 64) {
            int c = s1a - e0; if (c > 64) c = 64;
            int m = (lane < c) ? col[e0 + lane] : n;
            int jmr = (c + 7) >> 3;
            for (int jj = 0; jj < jmr; ++jj) {
                int sn = __shfl(m, jj * 8 + gx);
                v4u pp = *reinterpret_cast<const v4u*>(&hb_in[(size_t)sn * 32 + bo]);
                v4f lo, hi;
                unpack8(pp, lo, hi); aL0 += lo; aH0 += hi;
            }
        }
        for (int e0 = s0b + 64; e0 < s1b; e0 += 64) {
            int c = s1b - e0; if (c > 64) c = 64;
            int m = (lane < c) ? col[e0 + lane] : n;
            int jmr = (c + 7) >> 3;
            for (int jj = 0; jj < jmr; ++jj) {
                int sn = __shfl(m, jj * 8 + gx);
                v4u pp = *reinterpret_cast<const v4u*>(&hb_in[(size_t)sn * 32 + bo]);
                v4f lo, hi;
                unpack8(pp, lo, hi); bL0 += lo; bH0 += hi;
            }
        }
        v4f aLo = aL0 + aL1, aHi = aH0 + aH1;
        v4f bLo = bL0 + bL1, bHi = bH0 + bH1;
#pragma unroll
        for (int c = 0; c < 4; ++c) {
            aLo[c] += __shfl_xor(aLo[c], 8);
            aLo[c] += __shfl_xor(aLo[c], 16);
            aLo[c] += __shfl_xor(aLo[c], 32);
            aHi[c] += __shfl_xor(aHi[c], 8);
            aHi[c] += __shfl_xor(aHi[c], 16);
            aHi[c] += __shfl_xor(aHi[c], 32);
            bLo[c] += __shfl_xor(bLo[c], 8);
            bLo[c] += __shfl_xor(bLo[c], 16);
            bLo[c] += __shfl_xor(bLo[c], 32);
            bHi[c] += __shfl_xor(bHi[c], 8);
            bHi[c] += __shfl_xor(bHi[c], 16);
            bHi[c] += __shfl_xor(bHi[c], 32);
        }
        if (va && lane < 8) {
            float sc = (da > 0) ? 1.f / (float)da : 0.f;
            int fo = sl * 8;
            v4f s0 = *reinterpret_cast<const v4f*>(&hf_in[(size_t)na * HID + fo]);
            v4f s1 = *reinterpret_cast<const v4f*>(&hf_in[(size_t)na * HID + fo + 4]);
            *reinterpret_cast<v4f*>(&rst[(wid * 4 + p * 2) * RST_PITCH + fo]) =
                eps1 * s0 + aLo * sc;
            *reinterpret_cast<v4f*>(&rst[(wid * 4 + p * 2) * RST_PITCH + fo + 4]) =
                eps1 * s1 + aHi * sc;
        }
        if (vb && lane < 8) {
            float sc = (db > 0) ? 1.f / (float)db : 0.f;
            int fo = sl * 8;
            v4f s0 = *reinterpret_cast<const v4f*>(&hf_in[(size_t)nb * HID + fo]);
            v4f s1 = *reinterpret_cast<const v4f*>(&hf_in[(size_t)nb * HID + fo + 4]);
            *reinterpret_cast<v4f*>(&rst[(wid * 4 + p * 2 + 1) * RST_PITCH + fo]) =
                eps1 * s0 + bLo * sc;
            *reinterpret_cast<v4f*>(&rst[(wid * 4 + p * 2 + 1) * RST_PITCH + fo + 4]) =
                eps1 * s1 + bHi * sc;
        }
    }
    __syncthreads();

    // phase B: out = relu(rst @ W + b); 1 node x 4 outputs per thread
    int tx = threadIdx.x & 15;   // output quad
    int ty = threadIdx.x >> 4;   // node 0..31
    v4f a4 = *reinterpret_cast<const v4f*>(&bias[tx * 4]);
#pragma unroll 16
    for (int k = 0; k < HID; ++k) {
        v4f w4 = *reinterpret_cast<const v4f*>(&Wl[k * HID + tx * 4]);
        a4 += rst[ty * RST_PITCH + k] * w4;
    }
    int node = base + ty;
    if (node < n) {
        v4f o;
        o[0] = fmaxf(a4[0], 0.f); o[1] = fmaxf(a4[1], 0.f);
        o[2] = fmaxf(a4[2], 0.f); o[3] = fmaxf(a4[3], 0.f);
        *reinterpret_cast<v4f*>(&hf_out[(size_t)node * HID + tx * 4]) = o;
        if (!FINAL)
            *reinterpret_cast<uint2*>(&hb_out[(size_t)node * 32 + tx * 2]) = pack4(o);
    }
}

// ---------------- launch ----------------

extern "C" void kernel_launch(void* const* d_in, const int* in_sizes, int n_in,
                              void* d_out, int out_size, void* d_ws, size_t ws_size,
                              hipStream_t stream) {
    const float* feat = (const float*)d_in[0];
    const int*   src  = (const int*)d_in[1];
    const int*   dst  = (const int*)d_in[2];
    const float* fc_w = (const float*)d_in[3];
    const float* fc_b = (const float*)d_in[4];
    const float* w0   = (const float*)d_in[5];
    const float* b0   = (const float*)d_in[6];
    const float* w1   = (const float*)d_in[7];
    const float* b1   = (const float*)d_in[8];
    const float* w2   = (const float*)d_in[9];
    const float* b2   = (const float*)d_in[10];
    const float* eps  = (const float*)d_in[11];
    float* out = (float*)d_out;

    char* ws = (char*)d_ws;
    size_t off = 0;
    auto alloc = [&](size_t bytes) {
        size_t o = off;
        off += (bytes + 255) & ~(size_t)255;
        return (void*)(ws + o);
    };
    int*      row_ptr = (int*)alloc((size_t)(N_NODES + 1) * 4);
    int*      blksum  = (int*)alloc(256 * 4);
    int*      H       = (int*)alloc((size_t)NCHUNK * N_NODES * 4);  // 6.4 MB
    int*      P       = (int*)alloc((size_t)NCHUNK * N_NODES * 4);  // 6.4 MB
    int*      col     = (int*)alloc((size_t)N_EDGES * 4);
    float*    hAf     = (float*)alloc((size_t)N_NODES * HID * 4);
    float*    hBf     = (float*)alloc((size_t)N_NODES * HID * 4);
    unsigned* hAb     = (unsigned*)alloc((size_t)(N_NODES + 1) * 32 * 4); // bf16 mirror
    unsigned* hBb     = (unsigned*)alloc((size_t)(N_NODES + 1) * 32 * 4);

    const int csrBlocks = NXCD * NCHUNK;   // 256

    // fc_init (782 blocks) + hist (256 blocks) fused: independent subsystems
    fc_hist_kernel<<<FC_BLOCKS + csrBlocks, 256, 0, stream>>>(
        feat, fc_w, fc_b, hAf, hAb, dst, H, N_NODES);
    scanA_kernel<<<NBLK_N, 256, 0, stream>>>(H, row_ptr, blksum, hAb, hBb);
    scanB_kernel<<<NBLK_N, 256, 0, stream>>>(H, row_ptr, P, blksum);
    place_kernel<<<csrBlocks, 256, 0, stream>>>(src, dst, P, col);

    const int ginBlocks = (N_NODES + NT - 1) / NT;      // 1563
    gin_layer_kernel<false><<<ginBlocks, 512, 0, stream>>>(
        hAf, hAb, row_ptr, col, w0, b0, eps, 0, hBf, hBb, N_NODES);
    gin_layer_kernel<false><<<ginBlocks, 512, 0, stream>>>(
        hBf, hBb, row_ptr, col, w1, b1, eps, 1, hAf, hAb, N_NODES);
    gin_layer_kernel<true><<<ginBlocks, 512, 0, stream>>>(
        hAf, hAb, row_ptr, col, w2, b2, eps, 2, out, nullptr, N_NODES);
}

// Round 13
// 163.256 us; speedup vs baseline: 1.1088x; 1.1088x over previous
//
#include <hip/hip_runtime.h>

#define N_NODES 50000
#define N_EDGES 800000
#define IN_DIM 128
#define HID 64
#define NT 32        // nodes per block in gin layer
#define RST_PITCH 68 // 272B rows: 16B-aligned, conflict-free broadcasts
#define NXCD 8
#define RANGE (N_NODES / NXCD)             // 6250 nodes per range (25KB LDS)
#define NCHUNK 32
#define EDGES_PER_CHUNK (N_EDGES / NCHUNK) // 25000
#define I4_PER_CHUNK (EDGES_PER_CHUNK / 4) // 6250
#define NBLK_N 196                         // ceil(N_NODES/256)

using v4f = __attribute__((ext_vector_type(4))) float;
using v4i = __attribute__((ext_vector_type(4))) int;

// bf16x4 <-> f32x4 (RNE pack; unpack = shift/mask)
static __device__ inline uint2 pack4(v4f v) {
    unsigned u0 = __float_as_uint(v[0]);
    unsigned u1 = __float_as_uint(v[1]);
    unsigned u2 = __float_as_uint(v[2]);
    unsigned u3 = __float_as_uint(v[3]);
    uint2 r;
    r.x = ((u0 + 0x7FFFu + ((u0 >> 16) & 1)) >> 16) |
          ((u1 + 0x7FFFu + ((u1 >> 16) & 1)) & 0xFFFF0000u);
    r.y = ((u2 + 0x7FFFu + ((u2 >> 16) & 1)) >> 16) |
          ((u3 + 0x7FFFu + ((u3 >> 16) & 1)) & 0xFFFF0000u);
    return r;
}
static __device__ inline v4f unpack4(uint2 p) {
    v4f r;
    r[0] = __uint_as_float(p.x << 16);
    r[1] = __uint_as_float(p.x & 0xFFFF0000u);
    r[2] = __uint_as_float(p.y << 16);
    r[3] = __uint_as_float(p.y & 0xFFFF0000u);
    return r;
}

// ---------------- CSR build: atomic-free (LDS histograms) ----------------

__global__ __launch_bounds__(256) void hist_kernel(
        const int* __restrict__ dst, int* __restrict__ H) {
    __shared__ int cnt[RANGE];
    int r = blockIdx.x & (NXCD - 1), c = blockIdx.x >> 3;
    int lo = r * RANGE;
    for (int i = threadIdx.x; i < RANGE; i += 256) cnt[i] = 0;
    __syncthreads();
    const v4i* d4p = reinterpret_cast<const v4i*>(dst) + c * I4_PER_CHUNK;
#pragma unroll 2
    for (int i = threadIdx.x; i < I4_PER_CHUNK; i += 256) {
        v4i d4 = d4p[i];
        int a;
        a = d4.x - lo; if ((unsigned)a < RANGE) atomicAdd(&cnt[a], 1);
        a = d4.y - lo; if ((unsigned)a < RANGE) atomicAdd(&cnt[a], 1);
        a = d4.z - lo; if ((unsigned)a < RANGE) atomicAdd(&cnt[a], 1);
        a = d4.w - lo; if ((unsigned)a < RANGE) atomicAdd(&cnt[a], 1);
    }
    __syncthreads();
    int* Hrow = H + (size_t)c * N_NODES + lo;
    for (int i = threadIdx.x; i < RANGE; i += 256) Hrow[i] = cnt[i];
}

__global__ void scanA_kernel(const int* __restrict__ H, int* __restrict__ row_ptr,
                             int* __restrict__ blksum,
                             unsigned* __restrict__ hbA, unsigned* __restrict__ hbB) {
    __shared__ int sh[256];
    int t = threadIdx.x;
    int node = blockIdx.x * 256 + t;
    int d = 0;
    if (node < N_NODES)
#pragma unroll 8
        for (int c = 0; c < NCHUNK; ++c) d += H[(size_t)c * N_NODES + node];
    sh[t] = d;
    __syncthreads();
    for (int off = 1; off < 256; off <<= 1) {
        int add = (t >= off) ? sh[t - off] : 0;
        __syncthreads();
        sh[t] += add;
        __syncthreads();
    }
    int incl = sh[t];
    if (node < N_NODES) row_ptr[node] = incl - d;
    if (t == 255) blksum[blockIdx.x] = incl;
    if (blockIdx.x == 0 && t < 32) {
        hbA[(size_t)N_NODES * 32 + t] = 0u;
        hbB[(size_t)N_NODES * 32 + t] = 0u;
    }
}

__global__ void scanB_kernel(const int* __restrict__ H, int* __restrict__ row_ptr,
                             int* __restrict__ P, const int* __restrict__ blksum) {
    __shared__ int sh[256];
    int t = threadIdx.x;
    int v = (t < NBLK_N) ? blksum[t] : 0;
    sh[t] = v;
    __syncthreads();
    for (int off = 1; off < 256; off <<= 1) {
        int add = (t >= off) ? sh[t - off] : 0;
        __syncthreads();
        sh[t] += add;
        __syncthreads();
    }
    int excl = sh[t] - v;
    __syncthreads();
    sh[t] = excl;
    __syncthreads();
    int node = blockIdx.x * 256 + t;
    if (node < N_NODES) {
        int run = row_ptr[node] + sh[blockIdx.x];
        row_ptr[node] = run;
#pragma unroll 8
        for (int c = 0; c < NCHUNK; ++c) {
            P[(size_t)c * N_NODES + node] = run;
            run += H[(size_t)c * N_NODES + node];
        }
    }
    if (node == 0) row_ptr[N_NODES] = N_EDGES;
}

// place edges: LDS cursors (no global atomics); blockIdx%8 = range -> XCD
// affinity keeps each range's col segment in one L2.
__global__ __launch_bounds__(256) void place_kernel(
        const int* __restrict__ src, const int* __restrict__ dst,
        const int* __restrict__ P, int* __restrict__ col) {
    __shared__ int cur[RANGE];
    int r = blockIdx.x & (NXCD - 1), c = blockIdx.x >> 3;
    int lo = r * RANGE;
    const int* Pc = P + (size_t)c * N_NODES + lo;
    for (int i = threadIdx.x; i < RANGE; i += 256) cur[i] = Pc[i];
    __syncthreads();
    const v4i* d4p = reinterpret_cast<const v4i*>(dst) + c * I4_PER_CHUNK;
    const v4i* s4p = reinterpret_cast<const v4i*>(src) + c * I4_PER_CHUNK;
#pragma unroll 2
    for (int i = threadIdx.x; i < I4_PER_CHUNK; i += 256) {
        v4i d4 = d4p[i];
        v4i s4 = s4p[i];
        int a;
        a = d4.x - lo; if ((unsigned)a < RANGE) col[atomicAdd(&cur[a], 1)] = s4.x;
        a = d4.y - lo; if ((unsigned)a < RANGE) col[atomicAdd(&cur[a], 1)] = s4.y;
        a = d4.z - lo; if ((unsigned)a < RANGE) col[atomicAdd(&cur[a], 1)] = s4.z;
        a = d4.w - lo; if ((unsigned)a < RANGE) col[atomicAdd(&cur[a], 1)] = s4.w;
    }
}

// ---------------- fc_init: h0 = relu(features @ fc_w + fc_b) ----------------
// writes fp32 h + bf16 gather mirror

#define FT_PITCH 132
#define FCNT 64

__global__ __launch_bounds__(256) void fc_init_kernel(
        const float* __restrict__ feat, const float* __restrict__ W,
        const float* __restrict__ bias, float* __restrict__ hf,
        unsigned* __restrict__ hb, int n) {
    __shared__ float Wl[IN_DIM * HID];      // 32 KB
    __shared__ float ft[FCNT * FT_PITCH];   // 33 KB

    int base = blockIdx.x * FCNT;
    for (int i = threadIdx.x; i < IN_DIM * HID / 4; i += 256)
        *reinterpret_cast<v4f*>(&Wl[i * 4]) = *reinterpret_cast<const v4f*>(&W[i * 4]);
    {
        int f4 = threadIdx.x & 31;
        int r0 = threadIdx.x >> 5;
        for (int p = 0; p < 8; ++p) {
            int r = p * 8 + r0;
            int node = base + r;
            v4f v = {0.f, 0.f, 0.f, 0.f};
            if (node < n)
                v = *reinterpret_cast<const v4f*>(&feat[(size_t)node * IN_DIM + f4 * 4]);
            *reinterpret_cast<v4f*>(&ft[r * FT_PITCH + f4 * 4]) = v;
        }
    }
    __syncthreads();

    int tx = threadIdx.x & 15;
    int ty = threadIdx.x >> 4;
    v4f acc[4];
    v4f b4 = *reinterpret_cast<const v4f*>(&bias[tx * 4]);
    acc[0] = b4; acc[1] = b4; acc[2] = b4; acc[3] = b4;

#pragma unroll 16
    for (int k = 0; k < IN_DIM; ++k) {
        v4f w4 = *reinterpret_cast<const v4f*>(&Wl[k * HID + tx * 4]);
        float a0 = ft[(ty * 4 + 0) * FT_PITCH + k];
        float a1 = ft[(ty * 4 + 1) * FT_PITCH + k];
        float a2 = ft[(ty * 4 + 2) * FT_PITCH + k];
        float a3 = ft[(ty * 4 + 3) * FT_PITCH + k];
        acc[0] += a0 * w4;
        acc[1] += a1 * w4;
        acc[2] += a2 * w4;
        acc[3] += a3 * w4;
    }
#pragma unroll
    for (int i = 0; i < 4; ++i) {
        int node = base + ty * 4 + i;
        if (node < n) {
            v4f o;
            o[0] = fmaxf(acc[i][0], 0.f);
            o[1] = fmaxf(acc[i][1], 0.f);
            o[2] = fmaxf(acc[i][2], 0.f);
            o[3] = fmaxf(acc[i][3], 0.f);
            *reinterpret_cast<v4f*>(&hf[(size_t)node * HID + tx * 4]) = o;
            *reinterpret_cast<uint2*>(&hb[(size_t)node * 32 + tx * 2]) = pack4(o);
        }
    }
}

// ---------------- fused GIN layer (512 threads, NT=32) ----------------
// Phase A: 8 waves x 4 nodes as 2 pairs; uint2 gather (16 lanes/row, 4
// edges/insn) with the pair j-loop UNROLLED x4 -> 8 independent gather
// loads in flight per wave (targets outstanding-miss concurrency, the
// measured bottleneck). Overshoot slots (jm rounded to 4, pair-max) read
// the L1-hot zero pad row n: branch-free, convergent, no miss-BW cost.
// Phase B: 32x64x64 GEMM, 1 node x 4 outputs per thread, W in LDS.

template<bool FINAL>
__global__ __launch_bounds__(512) void gin_layer_kernel(
        const float* __restrict__ hf_in, const unsigned* __restrict__ hb_in,
        const int* __restrict__ row_ptr, const int* __restrict__ col,
        const float* __restrict__ W, const float* __restrict__ bias,
        const float* __restrict__ eps_arr, int layer,
        float* __restrict__ hf_out, unsigned* __restrict__ hb_out, int n) {
    __shared__ float Wl[HID * HID];         // 16 KB
    __shared__ float rst[NT * RST_PITCH];   // 8.7 KB

    for (int i = threadIdx.x; i < HID * HID / 4; i += 512)
        *reinterpret_cast<v4f*>(&Wl[i * 4]) = *reinterpret_cast<const v4f*>(&W[i * 4]);

    int wid = threadIdx.x >> 6, lane = threadIdx.x & 63;
    int gx = lane >> 4;         // edge subgroup 0..3
    int fq = lane & 15;         // feature quad id
    int fo = fq * 4;            // float offset
    int bo = fq * 2;            // uint offset in 32-uint bf16 row
    int base = blockIdx.x * NT;
    int n0 = base + wid * 4;    // this wave's 4 nodes
    float eps1 = 1.f + eps_arr[layer];

#pragma unroll
    for (int p = 0; p < 2; ++p) {
        int na = n0 + p * 2, nb = na + 1;
        bool va = na < n, vb = nb < n;
        int s0a = 0, s1a = 0, s0b = 0, s1b = 0;
        if (va) { s0a = row_ptr[na]; s1a = row_ptr[na + 1]; }
        if (vb) { s0b = row_ptr[nb]; s1b = row_ptr[nb + 1]; }
        int da = s1a - s0a, db = s1b - s0b;
        int ca = da > 64 ? 64 : da;
        int cb = db > 64 ? 64 : db;
        int myca = (va && lane < ca) ? col[s0a + lane] : n;   // pad -> zero row
        int mycb = (vb && lane < cb) ? col[s0b + lane] : n;
        v4f a0 = {0.f,0.f,0.f,0.f}, a1 = a0, c0 = a0, c1 = a0;
        int jma = (ca + 3) >> 2, jmb = (cb + 3) >> 2;
        int jm = jma > jmb ? jma : jmb;                       // <= 16
        for (int j = 0; j < jm; j += 4) {
            int i0 = j * 4 + gx;                              // <= 63 always
            int sa0 = __shfl(myca, i0);                       // convergent
            int sb0 = __shfl(mycb, i0);
            int sa1 = __shfl(myca, i0 + 4);
            int sb1 = __shfl(mycb, i0 + 4);
            int sa2 = __shfl(myca, i0 + 8);
            int sb2 = __shfl(mycb, i0 + 8);
            int sa3 = __shfl(myca, i0 + 12);
            int sb3 = __shfl(mycb, i0 + 12);
            // 8 independent loads issued before any consume
            uint2 pa0 = *reinterpret_cast<const uint2*>(&hb_in[(size_t)sa0 * 32 + bo]);
            uint2 pb0 = *reinterpret_cast<const uint2*>(&hb_in[(size_t)sb0 * 32 + bo]);
            uint2 pa1 = *reinterpret_cast<const uint2*>(&hb_in[(size_t)sa1 * 32 + bo]);
            uint2 pb1 = *reinterpret_cast<const uint2*>(&hb_in[(size_t)sb1 * 32 + bo]);
            uint2 pa2 = *reinterpret_cast<const uint2*>(&hb_in[(size_t)sa2 * 32 + bo]);
            uint2 pb2 = *reinterpret_cast<const uint2*>(&hb_in[(size_t)sb2 * 32 + bo]);
            uint2 pa3 = *reinterpret_cast<const uint2*>(&hb_in[(size_t)sa3 * 32 + bo]);
            uint2 pb3 = *reinterpret_cast<const uint2*>(&hb_in[(size_t)sb3 * 32 + bo]);
            a0 += unpack4(pa0);
            c0 += unpack4(pb0);
            a1 += unpack4(pa1);
            c1 += unpack4(pb1);
            a0 += unpack4(pa2);
            c0 += unpack4(pb2);
            a1 += unpack4(pa3);
            c1 += unpack4(pb3);
        }
        // remainder chunks (degree > 64) — rare, per node
        for (int e0 = s0a + 64; e0 < s1a; e0 += 64) {
            int c = s1a - e0; if (c > 64) c = 64;
            int m = (lane < c) ? col[e0 + lane] : n;
            int jmr = (c + 3) >> 2;
            for (int jj = 0; jj < jmr; ++jj) {
                int sn = __shfl(m, jj * 4 + gx);
                a0 += unpack4(*reinterpret_cast<const uint2*>(&hb_in[(size_t)sn * 32 + bo]));
            }
        }
        for (int e0 = s0b + 64; e0 < s1b; e0 += 64) {
            int c = s1b - e0; if (c > 64) c = 64;
            int m = (lane < c) ? col[e0 + lane] : n;
            int jmr = (c + 3) >> 2;
            for (int jj = 0; jj < jmr; ++jj) {
                int sn = __shfl(m, jj * 4 + gx);
                c0 += unpack4(*reinterpret_cast<const uint2*>(&hb_in[(size_t)sn * 32 + bo]));
            }
        }
        v4f acca = a0 + a1, accb = c0 + c1;
#pragma unroll
        for (int c = 0; c < 4; ++c) {
            acca[c] += __shfl_xor(acca[c], 16);
            acca[c] += __shfl_xor(acca[c], 32);
            accb[c] += __shfl_xor(accb[c], 16);
            accb[c] += __shfl_xor(accb[c], 32);
        }
        if (va && lane < 16) {
            float sc = (da > 0) ? 1.f / (float)da : 0.f;
            v4f self = *reinterpret_cast<const v4f*>(&hf_in[(size_t)na * HID + fo]);
            v4f rv = eps1 * self + acca * sc;
            *reinterpret_cast<v4f*>(&rst[(wid * 4 + p * 2) * RST_PITCH + fo]) = rv;
        }
        if (vb && lane < 16) {
            float sc = (db > 0) ? 1.f / (float)db : 0.f;
            v4f self = *reinterpret_cast<const v4f*>(&hf_in[(size_t)nb * HID + fo]);
            v4f rv = eps1 * self + accb * sc;
            *reinterpret_cast<v4f*>(&rst[(wid * 4 + p * 2 + 1) * RST_PITCH + fo]) = rv;
        }
    }
    __syncthreads();

    // phase B: out = relu(rst @ W + b); 1 node x 4 outputs per thread
    int tx = threadIdx.x & 15;   // output quad
    int ty = threadIdx.x >> 4;   // node 0..31
    v4f a4 = *reinterpret_cast<const v4f*>(&bias[tx * 4]);
#pragma unroll 16
    for (int k = 0; k < HID; ++k) {
        v4f w4 = *reinterpret_cast<const v4f*>(&Wl[k * HID + tx * 4]);
        a4 += rst[ty * RST_PITCH + k] * w4;
    }
    int node = base + ty;
    if (node < n) {
        v4f o;
        o[0] = fmaxf(a4[0], 0.f); o[1] = fmaxf(a4[1], 0.f);
        o[2] = fmaxf(a4[2], 0.f); o[3] = fmaxf(a4[3], 0.f);
        *reinterpret_cast<v4f*>(&hf_out[(size_t)node * HID + tx * 4]) = o;
        if (!FINAL)
            *reinterpret_cast<uint2*>(&hb_out[(size_t)node * 32 + tx * 2]) = pack4(o);
    }
}

// ---------------- launch ----------------

extern "C" void kernel_launch(void* const* d_in, const int* in_sizes, int n_in,
                              void* d_out, int out_size, void* d_ws, size_t ws_size,
                              hipStream_t stream) {
    const float* feat = (const float*)d_in[0];
    const int*   src  = (const int*)d_in[1];
    const int*   dst  = (const int*)d_in[2];
    const float* fc_w = (const float*)d_in[3];
    const float* fc_b = (const float*)d_in[4];
    const float* w0   = (const float*)d_in[5];
    const float* b0   = (const float*)d_in[6];
    const float* w1   = (const float*)d_in[7];
    const float* b1   = (const float*)d_in[8];
    const float* w2   = (const float*)d_in[9];
    const float* b2   = (const float*)d_in[10];
    const float* eps  = (const float*)d_in[11];
    float* out = (float*)d_out;

    char* ws = (char*)d_ws;
    size_t off = 0;
    auto alloc = [&](size_t bytes) {
        size_t o = off;
        off += (bytes + 255) & ~(size_t)255;
        return (void*)(ws + o);
    };
    int*      row_ptr = (int*)alloc((size_t)(N_NODES + 1) * 4);
    int*      blksum  = (int*)alloc(256 * 4);
    int*      H       = (int*)alloc((size_t)NCHUNK * N_NODES * 4);  // 6.4 MB
    int*      P       = (int*)alloc((size_t)NCHUNK * N_NODES * 4);  // 6.4 MB
    int*      col     = (int*)alloc((size_t)N_EDGES * 4);
    float*    hAf     = (float*)alloc((size_t)N_NODES * HID * 4);
    float*    hBf     = (float*)alloc((size_t)N_NODES * HID * 4);
    unsigned* hAb     = (unsigned*)alloc((size_t)(N_NODES + 1) * 32 * 4); // bf16 mirror
    unsigned* hBb     = (unsigned*)alloc((size_t)(N_NODES + 1) * 32 * 4);

    const int csrBlocks = NXCD * NCHUNK;   // 256

    hist_kernel<<<csrBlocks, 256, 0, stream>>>(dst, H);
    scanA_kernel<<<NBLK_N, 256, 0, stream>>>(H, row_ptr, blksum, hAb, hBb);
    scanB_kernel<<<NBLK_N, 256, 0, stream>>>(H, row_ptr, P, blksum);
    place_kernel<<<csrBlocks, 256, 0, stream>>>(src, dst, P, col);

    const int fcBlocks = (N_NODES + FCNT - 1) / FCNT;   // 782
    fc_init_kernel<<<fcBlocks, 256, 0, stream>>>(feat, fc_w, fc_b, hAf, hAb, N_NODES);

    const int ginBlocks = (N_NODES + NT - 1) / NT;      // 1563
    gin_layer_kernel<false><<<ginBlocks, 512, 0, stream>>>(
        hAf, hAb, row_ptr, col, w0, b0, eps, 0, hBf, hBb, N_NODES);
    gin_layer_kernel<false><<<ginBlocks, 512, 0, stream>>>(
        hBf, hBb, row_ptr, col, w1, b1, eps, 1, hAf, hAb, N_NODES);
    gin_layer_kernel<true><<<ginBlocks, 512, 0, stream>>>(
        hAf, hAb, row_ptr, col, w2, b2, eps, 2, out, nullptr, N_NODES);
}

// Round 14
// 149.422 us; speedup vs baseline: 1.2115x; 1.0926x over previous
//
#include <hip/hip_runtime.h>

#define N_NODES 50000
#define N_EDGES 800000
#define IN_DIM 128
#define HID 64
#define NT 32        // nodes per block in gin layer
#define RST_PITCH 68 // 272B rows: 16B-aligned, conflict-free broadcasts
#define NXCD 8
#define RANGE (N_NODES / NXCD)             // 6250 nodes per range (25KB LDS)
#define NCHUNK 32
#define EDGES_PER_CHUNK (N_EDGES / NCHUNK) // 25000
#define I4_PER_CHUNK (EDGES_PER_CHUNK / 4) // 6250
#define NBLK_N 196                         // ceil(N_NODES/256)

using v4f = __attribute__((ext_vector_type(4))) float;
using v4i = __attribute__((ext_vector_type(4))) int;

// bf16x4 <-> f32x4 (RNE pack; unpack = shift/mask, 4 VALU ops)
static __device__ inline uint2 pack4(v4f v) {
    unsigned u0 = __float_as_uint(v[0]);
    unsigned u1 = __float_as_uint(v[1]);
    unsigned u2 = __float_as_uint(v[2]);
    unsigned u3 = __float_as_uint(v[3]);
    uint2 r;
    r.x = ((u0 + 0x7FFFu + ((u0 >> 16) & 1)) >> 16) |
          ((u1 + 0x7FFFu + ((u1 >> 16) & 1)) & 0xFFFF0000u);
    r.y = ((u2 + 0x7FFFu + ((u2 >> 16) & 1)) >> 16) |
          ((u3 + 0x7FFFu + ((u3 >> 16) & 1)) & 0xFFFF0000u);
    return r;
}
static __device__ inline v4f unpack4(uint2 p) {
    v4f r;
    r[0] = __uint_as_float(p.x << 16);
    r[1] = __uint_as_float(p.x & 0xFFFF0000u);
    r[2] = __uint_as_float(p.y << 16);
    r[3] = __uint_as_float(p.y & 0xFFFF0000u);
    return r;
}

// ---------------- CSR build: atomic-free (LDS histograms) ----------------

__global__ __launch_bounds__(256) void hist_kernel(
        const int* __restrict__ dst, int* __restrict__ H) {
    __shared__ int cnt[RANGE];
    int r = blockIdx.x & (NXCD - 1), c = blockIdx.x >> 3;
    int lo = r * RANGE;
    for (int i = threadIdx.x; i < RANGE; i += 256) cnt[i] = 0;
    __syncthreads();
    const v4i* d4p = reinterpret_cast<const v4i*>(dst) + c * I4_PER_CHUNK;
#pragma unroll 2
    for (int i = threadIdx.x; i < I4_PER_CHUNK; i += 256) {
        v4i d4 = d4p[i];
        int a;
        a = d4.x - lo; if ((unsigned)a < RANGE) atomicAdd(&cnt[a], 1);
        a = d4.y - lo; if ((unsigned)a < RANGE) atomicAdd(&cnt[a], 1);
        a = d4.z - lo; if ((unsigned)a < RANGE) atomicAdd(&cnt[a], 1);
        a = d4.w - lo; if ((unsigned)a < RANGE) atomicAdd(&cnt[a], 1);
    }
    __syncthreads();
    int* Hrow = H + (size_t)c * N_NODES + lo;
    for (int i = threadIdx.x; i < RANGE; i += 256) Hrow[i] = cnt[i];
}

// deg = sum over chunks of H; block-local scan -> row_ptr + blksum.
// Also zeroes bf16 pad row n of both mirrors (gather pad target).
__global__ void scanA_kernel(const int* __restrict__ H, int* __restrict__ row_ptr,
                             int* __restrict__ blksum,
                             unsigned* __restrict__ hbA, unsigned* __restrict__ hbB) {
    __shared__ int sh[256];
    int t = threadIdx.x;
    int node = blockIdx.x * 256 + t;
    int d = 0;
    if (node < N_NODES)
#pragma unroll 8
        for (int c = 0; c < NCHUNK; ++c) d += H[(size_t)c * N_NODES + node];
    sh[t] = d;
    __syncthreads();
    for (int off = 1; off < 256; off <<= 1) {
        int add = (t >= off) ? sh[t - off] : 0;
        __syncthreads();
        sh[t] += add;
        __syncthreads();
    }
    int incl = sh[t];
    if (node < N_NODES) row_ptr[node] = incl - d;
    if (t == 255) blksum[blockIdx.x] = incl;
    if (blockIdx.x == 0 && t < 32) {
        hbA[(size_t)N_NODES * 32 + t] = 0u;
        hbB[(size_t)N_NODES * 32 + t] = 0u;
    }
}

// scan block sums (redundantly per block), finalize row_ptr, and emit
// per-(chunk,node) placement offsets P[c][node] = row_ptr + prefix_c(H).
__global__ void scanB_kernel(const int* __restrict__ H, int* __restrict__ row_ptr,
                             int* __restrict__ P, const int* __restrict__ blksum) {
    __shared__ int sh[256];
    int t = threadIdx.x;
    int v = (t < NBLK_N) ? blksum[t] : 0;
    sh[t] = v;
    __syncthreads();
    for (int off = 1; off < 256; off <<= 1) {
        int add = (t >= off) ? sh[t - off] : 0;
        __syncthreads();
        sh[t] += add;
        __syncthreads();
    }
    int excl = sh[t] - v;
    __syncthreads();
    sh[t] = excl;
    __syncthreads();
    int node = blockIdx.x * 256 + t;
    if (node < N_NODES) {
        int run = row_ptr[node] + sh[blockIdx.x];
        row_ptr[node] = run;
#pragma unroll 8
        for (int c = 0; c < NCHUNK; ++c) {
            P[(size_t)c * N_NODES + node] = run;
            run += H[(size_t)c * N_NODES + node];
        }
    }
    if (node == 0) row_ptr[N_NODES] = N_EDGES;
}

// place edges: LDS cursors (no global atomics); blockIdx%8 = range -> XCD
// affinity keeps each range's col segment in one L2.
__global__ __launch_bounds__(256) void place_kernel(
        const int* __restrict__ src, const int* __restrict__ dst,
        const int* __restrict__ P, int* __restrict__ col) {
    __shared__ int cur[RANGE];
    int r = blockIdx.x & (NXCD - 1), c = blockIdx.x >> 3;
    int lo = r * RANGE;
    const int* Pc = P + (size_t)c * N_NODES + lo;
    for (int i = threadIdx.x; i < RANGE; i += 256) cur[i] = Pc[i];
    __syncthreads();
    const v4i* d4p = reinterpret_cast<const v4i*>(dst) + c * I4_PER_CHUNK;
    const v4i* s4p = reinterpret_cast<const v4i*>(src) + c * I4_PER_CHUNK;
#pragma unroll 2
    for (int i = threadIdx.x; i < I4_PER_CHUNK; i += 256) {
        v4i d4 = d4p[i];
        v4i s4 = s4p[i];
        int a;
        a = d4.x - lo; if ((unsigned)a < RANGE) col[atomicAdd(&cur[a], 1)] = s4.x;
        a = d4.y - lo; if ((unsigned)a < RANGE) col[atomicAdd(&cur[a], 1)] = s4.y;
        a = d4.z - lo; if ((unsigned)a < RANGE) col[atomicAdd(&cur[a], 1)] = s4.z;
        a = d4.w - lo; if ((unsigned)a < RANGE) col[atomicAdd(&cur[a], 1)] = s4.w;
    }
}

// ---------------- fc_init: h0 = relu(features @ fc_w + fc_b) ----------------
// writes fp32 h + bf16 gather mirror

#define FT_PITCH 132
#define FCNT 64

__global__ __launch_bounds__(256) void fc_init_kernel(
        const float* __restrict__ feat, const float* __restrict__ W,
        const float* __restrict__ bias, float* __restrict__ hf,
        unsigned* __restrict__ hb, int n) {
    __shared__ float Wl[IN_DIM * HID];      // 32 KB
    __shared__ float ft[FCNT * FT_PITCH];   // 33 KB

    int base = blockIdx.x * FCNT;
    for (int i = threadIdx.x; i < IN_DIM * HID / 4; i += 256)
        *reinterpret_cast<v4f*>(&Wl[i * 4]) = *reinterpret_cast<const v4f*>(&W[i * 4]);
    {
        int f4 = threadIdx.x & 31;
        int r0 = threadIdx.x >> 5;
        for (int p = 0; p < 8; ++p) {
            int r = p * 8 + r0;
            int node = base + r;
            v4f v = {0.f, 0.f, 0.f, 0.f};
            if (node < n)
                v = *reinterpret_cast<const v4f*>(&feat[(size_t)node * IN_DIM + f4 * 4]);
            *reinterpret_cast<v4f*>(&ft[r * FT_PITCH + f4 * 4]) = v;
        }
    }
    __syncthreads();

    int tx = threadIdx.x & 15;
    int ty = threadIdx.x >> 4;
    v4f acc[4];
    v4f b4 = *reinterpret_cast<const v4f*>(&bias[tx * 4]);
    acc[0] = b4; acc[1] = b4; acc[2] = b4; acc[3] = b4;

#pragma unroll 16
    for (int k = 0; k < IN_DIM; ++k) {
        v4f w4 = *reinterpret_cast<const v4f*>(&Wl[k * HID + tx * 4]);
        float a0 = ft[(ty * 4 + 0) * FT_PITCH + k];
        float a1 = ft[(ty * 4 + 1) * FT_PITCH + k];
        float a2 = ft[(ty * 4 + 2) * FT_PITCH + k];
        float a3 = ft[(ty * 4 + 3) * FT_PITCH + k];
        acc[0] += a0 * w4;
        acc[1] += a1 * w4;
        acc[2] += a2 * w4;
        acc[3] += a3 * w4;
    }
#pragma unroll
    for (int i = 0; i < 4; ++i) {
        int node = base + ty * 4 + i;
        if (node < n) {
            v4f o;
            o[0] = fmaxf(acc[i][0], 0.f);
            o[1] = fmaxf(acc[i][1], 0.f);
            o[2] = fmaxf(acc[i][2], 0.f);
            o[3] = fmaxf(acc[i][3], 0.f);
            *reinterpret_cast<v4f*>(&hf[(size_t)node * HID + tx * 4]) = o;
            *reinterpret_cast<uint2*>(&hb[(size_t)node * 32 + tx * 2]) = pack4(o);
        }
    }
}

// ---------------- fused GIN layer (512 threads, NT=32) ----------------
// Phase A: 8 waves x 4 nodes as 2 pairs, j-loop unrolled x2 with split
// accumulators -> 4 independent gathers in flight. Gather reads the BF16
// mirror (8B/lane, half the bytes); self term + GEMM stay fp32.
// Tail lanes / overshoot read zero pad row n (convergent shfl, branch-free).
// Phase B: 32x64x64 GEMM, 1 node x 4 outputs per thread, W in LDS.
// FINAL=true writes fp32 only (to d_out); else fp32 h + bf16 mirror.

template<bool FINAL>
__global__ __launch_bounds__(512) void gin_layer_kernel(
        const float* __restrict__ hf_in, const unsigned* __restrict__ hb_in,
        const int* __restrict__ row_ptr, const int* __restrict__ col,
        const float* __restrict__ W, const float* __restrict__ bias,
        const float* __restrict__ eps_arr, int layer,
        float* __restrict__ hf_out, unsigned* __restrict__ hb_out, int n) {
    __shared__ float Wl[HID * HID];         // 16 KB
    __shared__ float rst[NT * RST_PITCH];   // 8.7 KB

    for (int i = threadIdx.x; i < HID * HID / 4; i += 512)
        *reinterpret_cast<v4f*>(&Wl[i * 4]) = *reinterpret_cast<const v4f*>(&W[i * 4]);

    int wid = threadIdx.x >> 6, lane = threadIdx.x & 63;
    int gx = lane >> 4;         // edge subgroup 0..3
    int fq = lane & 15;         // feature quad id
    int fo = fq * 4;            // float offset
    int bo = fq * 2;            // uint offset in bf16 row (32 uints/row)
    int base = blockIdx.x * NT;
    int n0 = base + wid * 4;    // this wave's 4 nodes
    float eps1 = 1.f + eps_arr[layer];

#pragma unroll
    for (int p = 0; p < 2; ++p) {
        int na = n0 + p * 2, nb = na + 1;
        bool va = na < n, vb = nb < n;
        int s0a = 0, s1a = 0, s0b = 0, s1b = 0;
        if (va) { s0a = row_ptr[na]; s1a = row_ptr[na + 1]; }
        if (vb) { s0b = row_ptr[nb]; s1b = row_ptr[nb + 1]; }
        int da = s1a - s0a, db = s1b - s0b;
        int ca = da > 64 ? 64 : da;
        int cb = db > 64 ? 64 : db;
        int myca = (va && lane < ca) ? col[s0a + lane] : n;   // pad -> zero row
        int mycb = (vb && lane < cb) ? col[s0b + lane] : n;
        v4f a0 = {0.f,0.f,0.f,0.f}, a1 = a0, c0 = a0, c1 = a0;
        int jma = (ca + 3) >> 2, jmb = (cb + 3) >> 2;
        int jm = jma > jmb ? jma : jmb;
        int j = 0;
        for (; j + 2 <= jm; j += 2) {
            int i0 = j * 4 + gx, i1 = i0 + 4;
            int sa0 = __shfl(myca, i0);                       // convergent
            int sb0 = __shfl(mycb, i0);
            int sa1 = __shfl(myca, i1);
            int sb1 = __shfl(mycb, i1);
            uint2 pa0 = *reinterpret_cast<const uint2*>(&hb_in[(size_t)sa0 * 32 + bo]);
            uint2 pb0 = *reinterpret_cast<const uint2*>(&hb_in[(size_t)sb0 * 32 + bo]);
            uint2 pa1 = *reinterpret_cast<const uint2*>(&hb_in[(size_t)sa1 * 32 + bo]);
            uint2 pb1 = *reinterpret_cast<const uint2*>(&hb_in[(size_t)sb1 * 32 + bo]);
            a0 += unpack4(pa0);
            c0 += unpack4(pb0);
            a1 += unpack4(pa1);
            c1 += unpack4(pb1);
        }
        if (j < jm) {
            int i0 = j * 4 + gx;
            int sa0 = __shfl(myca, i0);
            int sb0 = __shfl(mycb, i0);
            a0 += unpack4(*reinterpret_cast<const uint2*>(&hb_in[(size_t)sa0 * 32 + bo]));
            c0 += unpack4(*reinterpret_cast<const uint2*>(&hb_in[(size_t)sb0 * 32 + bo]));
        }
        // remainder chunks (degree > 64) — rare, per node
        for (int e0 = s0a + 64; e0 < s1a; e0 += 64) {
            int c = s1a - e0; if (c > 64) c = 64;
            int m = (lane < c) ? col[e0 + lane] : n;
            int jmr = (c + 3) >> 2;
            for (int jj = 0; jj < jmr; ++jj) {
                int sn = __shfl(m, jj * 4 + gx);
                a0 += unpack4(*reinterpret_cast<const uint2*>(&hb_in[(size_t)sn * 32 + bo]));
            }
        }
        for (int e0 = s0b + 64; e0 < s1b; e0 += 64) {
            int c = s1b - e0; if (c > 64) c = 64;
            int m = (lane < c) ? col[e0 + lane] : n;
            int jmr = (c + 3) >> 2;
            for (int jj = 0; jj < jmr; ++jj) {
                int sn = __shfl(m, jj * 4 + gx);
                c0 += unpack4(*reinterpret_cast<const uint2*>(&hb_in[(size_t)sn * 32 + bo]));
            }
        }
        v4f acca = a0 + a1, accb = c0 + c1;
#pragma unroll
        for (int c = 0; c < 4; ++c) {
            acca[c] += __shfl_xor(acca[c], 16);
            acca[c] += __shfl_xor(acca[c], 32);
            accb[c] += __shfl_xor(accb[c], 16);
            accb[c] += __shfl_xor(accb[c], 32);
        }
        if (va && lane < 16) {
            float sc = (da > 0) ? 1.f / (float)da : 0.f;
            v4f self = *reinterpret_cast<const v4f*>(&hf_in[(size_t)na * HID + fo]);
            v4f rv = eps1 * self + acca * sc;
            *reinterpret_cast<v4f*>(&rst[(wid * 4 + p * 2) * RST_PITCH + fo]) = rv;
        }
        if (vb && lane < 16) {
            float sc = (db > 0) ? 1.f / (float)db : 0.f;
            v4f self = *reinterpret_cast<const v4f*>(&hf_in[(size_t)nb * HID + fo]);
            v4f rv = eps1 * self + accb * sc;
            *reinterpret_cast<v4f*>(&rst[(wid * 4 + p * 2 + 1) * RST_PITCH + fo]) = rv;
        }
    }
    __syncthreads();

    // phase B: out = relu(rst @ W + b); 1 node x 4 outputs per thread
    int tx = threadIdx.x & 15;   // output quad
    int ty = threadIdx.x >> 4;   // node 0..31
    v4f a4 = *reinterpret_cast<const v4f*>(&bias[tx * 4]);
#pragma unroll 16
    for (int k = 0; k < HID; ++k) {
        v4f w4 = *reinterpret_cast<const v4f*>(&Wl[k * HID + tx * 4]);
        a4 += rst[ty * RST_PITCH + k] * w4;
    }
    int node = base + ty;
    if (node < n) {
        v4f o;
        o[0] = fmaxf(a4[0], 0.f); o[1] = fmaxf(a4[1], 0.f);
        o[2] = fmaxf(a4[2], 0.f); o[3] = fmaxf(a4[3], 0.f);
        *reinterpret_cast<v4f*>(&hf_out[(size_t)node * HID + tx * 4]) = o;
        if (!FINAL)
            *reinterpret_cast<uint2*>(&hb_out[(size_t)node * 32 + tx * 2]) = pack4(o);
    }
}

// ---------------- launch ----------------

extern "C" void kernel_launch(void* const* d_in, const int* in_sizes, int n_in,
                              void* d_out, int out_size, void* d_ws, size_t ws_size,
                              hipStream_t stream) {
    const float* feat = (const float*)d_in[0];
    const int*   src  = (const int*)d_in[1];
    const int*   dst  = (const int*)d_in[2];
    const float* fc_w = (const float*)d_in[3];
    const float* fc_b = (const float*)d_in[4];
    const float* w0   = (const float*)d_in[5];
    const float* b0   = (const float*)d_in[6];
    const float* w1   = (const float*)d_in[7];
    const float* b1   = (const float*)d_in[8];
    const float* w2   = (const float*)d_in[9];
    const float* b2   = (const float*)d_in[10];
    const float* eps  = (const float*)d_in[11];
    float* out = (float*)d_out;

    char* ws = (char*)d_ws;
    size_t off = 0;
    auto alloc = [&](size_t bytes) {
        size_t o = off;
        off += (bytes + 255) & ~(size_t)255;
        return (void*)(ws + o);
    };
    int*      row_ptr = (int*)alloc((size_t)(N_NODES + 1) * 4);
    int*      blksum  = (int*)alloc(256 * 4);
    int*      H       = (int*)alloc((size_t)NCHUNK * N_NODES * 4);  // 6.4 MB
    int*      P       = (int*)alloc((size_t)NCHUNK * N_NODES * 4);  // 6.4 MB
    int*      col     = (int*)alloc((size_t)N_EDGES * 4);
    float*    hAf     = (float*)alloc((size_t)N_NODES * HID * 4);
    float*    hBf     = (float*)alloc((size_t)N_NODES * HID * 4);
    unsigned* hAb     = (unsigned*)alloc((size_t)(N_NODES + 1) * 32 * 4); // bf16 mirror
    unsigned* hBb     = (unsigned*)alloc((size_t)(N_NODES + 1) * 32 * 4);

    const int csrBlocks = NXCD * NCHUNK;   // 256

    hist_kernel<<<csrBlocks, 256, 0, stream>>>(dst, H);
    scanA_kernel<<<NBLK_N, 256, 0, stream>>>(H, row_ptr, blksum, hAb, hBb);
    scanB_kernel<<<NBLK_N, 256, 0, stream>>>(H, row_ptr, P, blksum);
    place_kernel<<<csrBlocks, 256, 0, stream>>>(src, dst, P, col);

    const int fcBlocks = (N_NODES + FCNT - 1) / FCNT;   // 782
    fc_init_kernel<<<fcBlocks, 256, 0, stream>>>(feat, fc_w, fc_b, hAf, hAb, N_NODES);

    const int ginBlocks = (N_NODES + NT - 1) / NT;      // 1563
    gin_layer_kernel<false><<<ginBlocks, 512, 0, stream>>>(
        hAf, hAb, row_ptr, col, w0, b0, eps, 0, hBf, hBb, N_NODES);
    gin_layer_kernel<false><<<ginBlocks, 512, 0, stream>>>(
        hBf, hBb, row_ptr, col, w1, b1, eps, 1, hAf, hAb, N_NODES);
    gin_layer_kernel<true><<<ginBlocks, 512, 0, stream>>>(
        hAf, hAb, row_ptr, col, w2, b2, eps, 2, out, nullptr, N_NODES);
}